// Round 7
// baseline (274.978 us; speedup 1.0000x reference)
//
#include <hip/hip_runtime.h>
#include <cstdint>
#include <cstddef>

// ---------------------------------------------------------------------------
// SpatialGRU 32x32, B=64, U=64, C=64. Persistent: 32 rows x 4 batch-tiles
// (bid = row*4+bt). Flag-free handoff: h crosses WGs as packed 2xf16 dwords
// with LSB=1 validity (0xAA poison fails the test). R7: 2-barrier cell —
//   [A] poll+stage -> s1 -> [B] GEMM1 (waves 0-6, fused sigmoid) -> s2 ->
//   [C] GEMM2 n-split full-K (waves 4-7, 16 cols each) + epilogue + handoff.
// No k-split reduction (pacc gone). Parity double-buffering on qs32-hT and
// qf-s kills the WAR races of waves 0-3 running ahead into [A](j+1).
// ---------------------------------------------------------------------------

#define LDIM   32
#define BATCH  64
#define UNITS  64
#define CHAN   64
#define NBT    4
#define BT     16
#define TPB    512

typedef _Float16 f16;
typedef _Float16 f16x8 __attribute__((ext_vector_type(8)));
typedef float    f32x4 __attribute__((ext_vector_type(4)));

__global__ __launch_bounds__(TPB, 2) void spatial_gru_kernel(
    const float* __restrict__ x,     // (B, C, 32, 32)
    const float* __restrict__ W,     // (256, 448)
    const float* __restrict__ Urec,  // (192, 64)
    const float* __restrict__ bias,  // (512,)
    const float* __restrict__ Wij,   // (64, 64)
    float* __restrict__ out,         // (B, U)
    uint32_t* __restrict__ hbuf)     // (32,32,NBT,n=64,p=8) dwords
{
    const int bid = blockIdx.x;
    const int row = bid >> 2;
    const int bt  = bid & 3;
    const int b0  = bt * BT;
    const int t   = (int)threadIdx.x;
    const int u   = t & 63;
    const int g   = t >> 6;          // wave id 0..7 (uniform)
    const int l15 = t & 15;          // MFMA col lane / A-row (batch)
    const int lq  = (t & 63) >> 4;   // MFMA k-quad / C-row quad

    // ---- LDS ----
    // qf  : GEMM1 A (f16) [b][k]: hT 0:64 | hL 64:128 | hD 128:192 | s_even 192:256 | s_odd 256:320
    // rf  : GEMM2 A (f16) [b][k]: r*{hL,hT,hD} 0:192
    // qs32: fp32 state [b][c]: hT_even 0:64 | hL 64:128 | hD 128:192 | hT_odd 192:256
    // Gsz : z logits fp32 [b][n] 0:256
    __shared__ __attribute__((aligned(16))) f16 qf[BT][328];
    __shared__ __attribute__((aligned(16))) f16 rf[BT][200];
    __shared__ float qs32[BT][260];
    __shared__ float Gsz [BT][260];

    // ---- GEMM1 weights resident (waves 0..6: 64 cols each) ----
    f16x8 wreg[4][8];
    float bias1[4] = {0.f, 0.f, 0.f, 0.f};
    if (g < 7) {
        const int nb = g * 64 + l15;
#pragma unroll
        for (int T = 0; T < 4; ++T) {
            bias1[T] = bias[nb + 16 * T];
#pragma unroll
            for (int s = 0; s < 8; ++s) {
                f16x8 v;
#pragma unroll
                for (int jj = 0; jj < 8; ++jj) {
                    int kk = s * 32 + lq * 8 + jj;
                    v[jj] = (f16)W[(size_t)kk * 448 + nb + 16 * T];
                }
                wreg[T][s] = v;
            }
        }
    }
    // ---- GEMM2 weights: n-split — wave (g&3) owns cols 16*(g&3)..+16, FULL K ----
    f16x8 wreg2[8];
    const int n2 = (g & 3) * 16 + l15;       // this wave's GEMM2 col (waves 4..7)
    {
#pragma unroll
        for (int s = 0; s < 8; ++s) {
            f16x8 v;
#pragma unroll
            for (int jj = 0; jj < 8; ++jj) {
                int kk = s * 32 + lq * 8 + jj;
                float wv = (kk < 192) ? Urec[kk * 64 + n2] : Wij[(kk - 192) * 64 + n2];
                v[jj] = (f16)wv;
            }
            wreg2[s] = v;
        }
    }
    const float bias2 = bias[448 + n2];

    // ---- zero hL/hD regions (states0 == 0) ----
    for (int idx = t; idx < 128 * BT; idx += TPB) {
        int b = idx & 15, k = 64 + (idx >> 4);
        qs32[b][k] = 0.f;
        qf[b][k] = (f16)0.f;
    }

    // x: thread (g,u) owns batches 2g, 2g+1 at channel u
    const size_t xb0 = (size_t)(b0 + 2 * g) * 65536 + (size_t)u * 1024 + (size_t)row * 32;
    const size_t xb1 = xb0 + 65536;
    float nx0 = x[xb0], nx1 = x[xb1];
    __syncthreads();   // zero-init visible

    for (int j = 0; j < LDIM; ++j) {
        const int par = j & 1;
        const int sof = 192 + par * 64;     // qf s-region base (parity)
        const int hTb = par ? 192 : 0;      // qs32 hT-region base (parity)

        // ---- [A] stage x; poll packed hT dword; stage hT ----
        qf[2 * g][sof + u]     = (f16)nx0;
        qf[2 * g + 1][sof + u] = (f16)nx1;
        float ht0 = 0.f, ht1 = 0.f;
        f16 hf0 = (f16)0.f, hf1 = (f16)0.f;
        if (row > 0) {
            const uint32_t* sp =
                hbuf + ((((size_t)(row - 1) * LDIM + j) * NBT + bt) << 9) + (u << 3) + g;
            uint32_t w = __hip_atomic_load(sp, __ATOMIC_RELAXED, __HIP_MEMORY_SCOPE_AGENT);
            while ((w & 0x00010001u) != 0x00010001u) {
                __builtin_amdgcn_s_sleep(1);
                w = __hip_atomic_load(sp, __ATOMIC_RELAXED, __HIP_MEMORY_SCOPE_AGENT);
            }
            hf0 = __builtin_bit_cast(f16, (uint16_t)(w & 0xFFFFu));
            hf1 = __builtin_bit_cast(f16, (uint16_t)(w >> 16));
            ht0 = (float)hf0;
            ht1 = (float)hf1;
        }
        qs32[2 * g][hTb + u]     = ht0;  qf[2 * g][u]     = hf0;
        qs32[2 * g + 1][hTb + u] = ht1;  qf[2 * g + 1][u] = hf1;
        __syncthreads();   // s1 — staging complete

        // prefetch next cell's x (consumed next [A])
        if (j < LDIM - 1) { nx0 = x[xb0 + j + 1]; nx1 = x[xb1 + j + 1]; }

        // ---- [B] GEMM1 (waves 0..6) + fused sigmoid on waves 0..2 ----
        if (g < 7) {
            f32x4 acc[4];
#pragma unroll
            for (int T = 0; T < 4; ++T)
                acc[T] = (f32x4){bias1[T], bias1[T], bias1[T], bias1[T]};
#pragma unroll
            for (int s = 0; s < 8; ++s) {
                const int off = (s < 6) ? s * 32 : sof + (s - 6) * 32;
                f16x8 a = *(const f16x8*)&qf[l15][off + lq * 8];
#pragma unroll
                for (int T = 0; T < 4; ++T)
                    acc[T] = __builtin_amdgcn_mfma_f32_16x16x32_f16(a, wreg[T][s], acc[T], 0, 0, 0);
            }
            if (g < 3) {
                // rf k-blocks: 0:64 = r*hL, 64:128 = r*hT(parity), 128:192 = r*hD
                const int colbase = (g == 0) ? 64 : (g == 1) ? hTb : 128;
#pragma unroll
                for (int T = 0; T < 4; ++T)
#pragma unroll
                    for (int r = 0; r < 4; ++r) {
                        float rr = 1.f / (1.f + __expf(-acc[T][r]));
                        int b = lq * 4 + r;
                        float hv = qs32[b][colbase + T * 16 + l15];
                        rf[b][g * 64 + T * 16 + l15] = (f16)(rr * hv);
                    }
            } else {
                const int zb = (g - 3) * 64;
#pragma unroll
                for (int T = 0; T < 4; ++T)
#pragma unroll
                    for (int r = 0; r < 4; ++r)
                        Gsz[lq * 4 + r][zb + T * 16 + l15] = acc[T][r];
            }
        }
        __syncthreads();   // s2 — rf + Gsz ready

        // ---- [C] GEMM2 n-split full-K (waves 4..7) + epilogue + handoff ----
        if (g >= 4) {
            f32x4 a2 = (f32x4){bias2, bias2, bias2, bias2};
#pragma unroll
            for (int s = 0; s < 6; ++s) {
                f16x8 a = *(const f16x8*)&rf[l15][s * 32 + lq * 8];
                a2 = __builtin_amdgcn_mfma_f32_16x16x32_f16(a, wreg2[s], a2, 0, 0, 0);
            }
#pragma unroll
            for (int s = 6; s < 8; ++s) {
                f16x8 a = *(const f16x8*)&qf[l15][sof + (s - 6) * 32 + lq * 8];
                a2 = __builtin_amdgcn_mfma_f32_16x16x32_f16(a, wreg2[s], a2, 0, 0, 0);
            }
            // epilogue: lane owns batches 4*lq..4*lq+3, col n2
            uint32_t pk[2] = {0u, 0u};
#pragma unroll
            for (int r = 0; r < 4; ++r) {
                const int b = lq * 4 + r;
                float e2 = __expf(2.f * a2[r]);
                float th = 1.f - 2.f / (e2 + 1.f);      // tanh(h_hat logit)
                float zi = Gsz[b][n2],       zl = Gsz[b][64 + n2];
                float zt = Gsz[b][128 + n2], zd = Gsz[b][192 + n2];
                float mx = fmaxf(fmaxf(zi, zl), fmaxf(zt, zd));
                float ei = __expf(zi - mx), el = __expf(zl - mx);
                float et = __expf(zt - mx), ed = __expf(zd - mx);
                float inv = 1.f / (ei + el + et + ed);
                float hT = qs32[b][hTb + n2], hL = qs32[b][64 + n2], hD = qs32[b][128 + n2];
                float hv = (el * hL + et * hT + ed * hD + ei * th) * inv;
                // rotate (owner lane): hD <- hT, hL <- h_new
                qs32[b][128 + n2] = hT;
                qs32[b][64 + n2]  = hv;
                qf[b][128 + n2] = (f16)hT;
                qf[b][64 + n2]  = (f16)hv;
                if (row == LDIM - 1 && j == LDIM - 1)
                    out[(size_t)(b0 + b) * UNITS + n2] = hv;
                uint32_t h16 = (uint32_t)(__builtin_bit_cast(uint16_t, (f16)hv) | 1u);
                pk[r >> 1] |= h16 << ((r & 1) * 16);
            }
            // handoff: batches (4lq,4lq+1) -> pair 2lq, (4lq+2,4lq+3) -> 2lq+1
            uint64_t pw = ((uint64_t)pk[1] << 32) | pk[0];
            uint64_t* dst = (uint64_t*)(
                hbuf + ((((size_t)row * LDIM + j) * NBT + bt) << 9) + (n2 << 3) + 2 * lq);
            __hip_atomic_store(dst, pw, __ATOMIC_RELAXED, __HIP_MEMORY_SCOPE_AGENT);
        }
        // no third barrier: waves 0-3 fall through to next [A] (disjoint slots;
        // parity buffers cover qs32-hT and qf-s WAR races)
    }
}

extern "C" void kernel_launch(void* const* d_in, const int* in_sizes, int n_in,
                              void* d_out, int out_size, void* d_ws, size_t ws_size,
                              hipStream_t stream) {
    const float* x    = (const float*)d_in[0];
    const float* W    = (const float*)d_in[1];
    const float* Urec = (const float*)d_in[2];
    const float* bias = (const float*)d_in[3];
    const float* Wij  = (const float*)d_in[4];
    float* out = (float*)d_out;

    // hbuf: 32*32*4*512 dwords = 8 MB; poison 0xAAAAAAAA fails LSB validity.
    uint32_t* hbuf = (uint32_t*)d_ws;

    spatial_gru_kernel<<<LDIM * NBT, TPB, 0, stream>>>(
        x, W, Urec, bias, Wij, out, hbuf);
}